// Round 5
// baseline (1406.999 us; speedup 1.0000x reference)
//
#include <hip/hip_runtime.h>
#include <hip/hip_fp16.h>

// GAT layer: messages = X@Wm^T; e = lrelu(sf[src]+st[dst]); softmax over dst;
// merged = segsum(alpha * messages[src]); out = sig(c)*(X@Wr^T) + relu(merged).
//
// R4: k_scatter's per-node CSR had 16x write amplification (105 MB HBM writes
// for a 6.4 MB array; frontier = 100K dirty lines > L2). Replaced with
// 16-node bucket partition: frontier 6250 lines = 400 KB (L2-resident),
// histogram/scan over 6250 not 100K. k_bagg aggregates per bucket in LDS
// (ds_add_f32), one edge per wave, fp16 gather + f32 accumulate.

#define DD 128
#define NPB 32           // nodes per block in the GEMM kernel
#define LEAKY 0.01f
#define BSH 4            // log2(nodes per bucket)
#define BSZ 16           // nodes per bucket
#define CHK 1024         // edges per k_bagg chunk

#define FMA4(A, XS, W)                                        \
  A.x = fmaf((XS), (W).x, A.x); A.y = fmaf((XS), (W).y, A.y); \
  A.z = fmaf((XS), (W).z, A.z); A.w = fmaf((XS), (W).w, A.w)

// ---------- tiny helpers ----------
__global__ void k_transpose2(const float* __restrict__ Wm, const float* __restrict__ Wr,
                             float* __restrict__ WTm, float* __restrict__ WTr) {
  int idx = blockIdx.x * blockDim.x + threadIdx.x;
  if (idx < DD * DD) {
    int j = idx >> 7, k = idx & (DD - 1);
    WTm[k * DD + j] = Wm[idx];   // WT[k][j] = W[j][k]
    WTr[k * DD + j] = Wr[idx];
  }
}

__global__ void k_zero(int* __restrict__ p, int n) {
  int i = blockIdx.x * blockDim.x + threadIdx.x;
  if (i < n) p[i] = 0;
}

// Detect whether the edges buffer is int64 (odd int32 words all zero) or int32.
__global__ void k_detect(const int* __restrict__ e, int* __restrict__ flag) {
  if (threadIdx.x == 0 && blockIdx.x == 0) {
    int all0 = 1;
    for (int i = 0; i < 64; ++i)
      if (e[2 * i + 1] != 0) { all0 = 0; break; }
    flag[0] = all0;  // 1 -> int64 layout
  }
}

// Exact check: is W_res the identity? (one block, 256 threads)
__global__ void k_eye(const float* __restrict__ Wr, int* __restrict__ eyeflag) {
  __shared__ int ok_s;
  if (threadIdx.x == 0) ok_s = 1;
  __syncthreads();
  int ok = 1;
  for (int i = threadIdx.x; i < DD * DD; i += 256) {
    float expect = ((i >> 7) == (i & (DD - 1))) ? 1.f : 0.f;
    if (Wr[i] != expect) ok = 0;
  }
  if (!ok) ok_s = 0;  // benign race: all writers write 0
  __syncthreads();
  if (threadIdx.x == 0) eyeflag[0] = ok_s;
}

// ---------- fused GEMM: messages + scores + passthrough ----------
__global__ __launch_bounds__(256) void k_msg(
    const float* __restrict__ x, const float* __restrict__ WTm,
    const float* __restrict__ WTr, const float* __restrict__ attn_w,
    const float* __restrict__ coef, const int* __restrict__ eyeflag, int n_nodes,
    __half* __restrict__ mh, float* __restrict__ s_from,
    float* __restrict__ s_to, float* __restrict__ out) {
  __shared__ float4 lw4[32 * 32];    // one chunk: 32 k-rows x 32 float4-cols, 16 KiB
  __shared__ float4 lx4[NPB * 32];   // 32 node rows x 32 float4, 16 KiB
  __shared__ float lds_aw[2 * DD];   // 1 KiB
  const int t = threadIdx.x;
  const int base = blockIdx.x * NPB;
  const int nvalid = min(NPB, n_nodes - base);

  // stage X rows (flat copy, coalesced float4)
  const float4* xs = (const float4*)(x + (size_t)base * DD);
  const int nflt4 = nvalid * 32;
  for (int i = t; i < nflt4; i += 256) lx4[i] = xs[i];
  if (t < 2 * DD) lds_aw[t] = attn_w[t];

  const int j4 = t & 31;   // float4-column (outputs 4*j4..4*j4+3)
  const int g = t >> 5;    // node group (half-wave uniform)
  const int r0 = (g * 4 + 0) * 32, r1 = r0 + 32, r2 = r1 + 32, r3 = r2 + 32;

  float4 a0, a1, a2, a3;

  // Named accumulators, bounded unroll -> no spill (R1 lesson: full unroll
  // hit 256 VGPR + 6.4 GB scratch traffic).
#define GEMM128(WT)                                                           \
  a0 = a1 = a2 = a3 = make_float4(0.f, 0.f, 0.f, 0.f);                        \
  _Pragma("unroll 1")                                                         \
  for (int chunk = 0; chunk < 4; ++chunk) {                                   \
    __syncthreads();                                                          \
    const float4* wsrc = (const float4*)((WT) + chunk * 32 * DD);             \
    lw4[t] = wsrc[t];                                                         \
    lw4[t + 256] = wsrc[t + 256];                                             \
    lw4[t + 512] = wsrc[t + 512];                                             \
    lw4[t + 768] = wsrc[t + 768];                                             \
    __syncthreads();                                                          \
    const int xb = chunk * 8;                                                 \
    _Pragma("unroll 2")                                                       \
    for (int k = 0; k < 32; k += 4) {                                         \
      float4 w0 = lw4[(k + 0) * 32 + j4];                                     \
      float4 w1 = lw4[(k + 1) * 32 + j4];                                     \
      float4 w2 = lw4[(k + 2) * 32 + j4];                                     \
      float4 w3 = lw4[(k + 3) * 32 + j4];                                     \
      float4 x0 = lx4[r0 + xb + (k >> 2)];                                    \
      float4 x1 = lx4[r1 + xb + (k >> 2)];                                    \
      float4 x2 = lx4[r2 + xb + (k >> 2)];                                    \
      float4 x3 = lx4[r3 + xb + (k >> 2)];                                    \
      FMA4(a0, x0.x, w0); FMA4(a0, x0.y, w1);                                 \
      FMA4(a0, x0.z, w2); FMA4(a0, x0.w, w3);                                 \
      FMA4(a1, x1.x, w0); FMA4(a1, x1.y, w1);                                 \
      FMA4(a1, x1.z, w2); FMA4(a1, x1.w, w3);                                 \
      FMA4(a2, x2.x, w0); FMA4(a2, x2.y, w1);                                 \
      FMA4(a2, x2.z, w2); FMA4(a2, x2.w, w3);                                 \
      FMA4(a3, x3.x, w0); FMA4(a3, x3.y, w1);                                 \
      FMA4(a3, x3.z, w2); FMA4(a3, x3.w, w3);                                 \
    }                                                                         \
  }

  // ---- phase A: messages = X @ Wm^T (fp16 store), plus attention scores ----
  GEMM128(WTm);
  {
    float4 av[4] = {a0, a1, a2, a3};
#pragma unroll
    for (int b = 0; b < 4; ++b) {
      int n = g * 4 + b;
      if (n < nvalid) {   // uniform across the 32-lane group
        int gn = base + n;
        float4 v = av[b];
        union { __half2 h2[2]; uint2 u; } pk;
        pk.h2[0] = __floats2half2_rn(v.x, v.y);
        pk.h2[1] = __floats2half2_rn(v.z, v.w);
        ((uint2*)(mh + (size_t)gn * DD))[j4] = pk.u;
        float sf = v.x * lds_aw[4 * j4] + v.y * lds_aw[4 * j4 + 1] +
                   v.z * lds_aw[4 * j4 + 2] + v.w * lds_aw[4 * j4 + 3];
        float stv = v.x * lds_aw[DD + 4 * j4] + v.y * lds_aw[DD + 4 * j4 + 1] +
                    v.z * lds_aw[DD + 4 * j4 + 2] + v.w * lds_aw[DD + 4 * j4 + 3];
#pragma unroll
        for (int m = 16; m; m >>= 1) {
          sf += __shfl_xor(sf, m, 32);
          stv += __shfl_xor(stv, m, 32);
        }
        if (j4 == 0) { s_from[gn] = sf; s_to[gn] = stv; }
      }
    }
  }

  // ---- phase B: passthrough = sig(c) * (X @ Wr^T) -> d_out ----
  const float sig = 1.f / (1.f + __expf(-coef[0]));
  if (eyeflag[0]) {
    // W_res == I (the reference init): passthrough = sig * x. lds_x intact.
    float4* od = (float4*)(out + (size_t)base * DD);
    for (int i = t; i < nflt4; i += 256) {
      float4 v = lx4[i];
      v.x *= sig; v.y *= sig; v.z *= sig; v.w *= sig;
      od[i] = v;
    }
  } else {
    GEMM128(WTr);
    float4 av[4] = {a0, a1, a2, a3};
#pragma unroll
    for (int b = 0; b < 4; ++b) {
      int n = g * 4 + b;
      if (n < nvalid) {
        int gn = base + n;
        float4 v = av[b];
        v.x *= sig; v.y *= sig; v.z *= sig; v.w *= sig;
        ((float4*)(out + (size_t)gn * DD))[j4] = v;
      }
    }
  }
#undef GEMM128
}

// ---------- bucket partition (dst >> 4) ----------
__global__ void k_bcount(const int* __restrict__ edges, int n_edges, int n_nodes,
                         const int* __restrict__ flag, int* __restrict__ bcnt) {
  int i = blockIdx.x * blockDim.x + threadIdx.x;
  if (i < n_edges) {
    int d = flag[0] ? ((const int2*)edges)[n_edges + i].x : edges[n_edges + i];
    if ((unsigned)d < (unsigned)n_nodes) atomicAdd(&bcnt[d >> BSH], 1);
  }
}

// Single-block scan over nb buckets (nb ~ 6250), chunked 1024 at a time.
__global__ __launch_bounds__(256) void k_bscan(const int* __restrict__ cnt, int nb,
                                               int* __restrict__ bstart,
                                               int* __restrict__ bcursor) {
  __shared__ int lds[256];
  __shared__ int carry_s;
  const int t = threadIdx.x;
  if (t == 0) carry_s = 0;
  __syncthreads();
  const int nchunks = (nb + 1023) / 1024;
  for (int c = 0; c < nchunks; ++c) {
    const int carry = carry_s;
    const int base = c * 1024 + t * 4;
    int v0 = 0, v1 = 0, v2 = 0, v3 = 0;
    if (base + 0 < nb) v0 = cnt[base + 0];
    if (base + 1 < nb) v1 = cnt[base + 1];
    if (base + 2 < nb) v2 = cnt[base + 2];
    if (base + 3 < nb) v3 = cnt[base + 3];
    const int tsum = v0 + v1 + v2 + v3;
    int val = tsum;
    lds[t] = val;
    __syncthreads();
    for (int off = 1; off < 256; off <<= 1) {
      int a = (t >= off) ? lds[t - off] : 0;
      __syncthreads();
      val += a;
      lds[t] = val;
      __syncthreads();
    }
    int o0 = carry + val - tsum;
    int o1 = o0 + v0, o2 = o1 + v1, o3 = o2 + v2;
    if (base + 0 < nb) { bstart[base + 0] = o0; bcursor[base + 0] = o0; }
    if (base + 1 < nb) { bstart[base + 1] = o1; bcursor[base + 1] = o1; }
    if (base + 2 < nb) { bstart[base + 2] = o2; bcursor[base + 2] = o2; }
    if (base + 3 < nb) { bstart[base + 3] = o3; bcursor[base + 3] = o3; }
    __syncthreads();
    if (t == 255) carry_s = carry + val;
    __syncthreads();
  }
  if (t == 0) bstart[nb] = carry_s;
}

// Scatter packed (src<<4 | dst&15) into bucket-contiguous regions.
// Write frontier = nb lines = 400 KB -> L2-resident, no dirty-line thrash.
__global__ void k_bscatter(const int* __restrict__ edges, int n_edges, int n_nodes,
                           const int* __restrict__ flag, int* __restrict__ bcursor,
                           int* __restrict__ packed) {
  int i = blockIdx.x * blockDim.x + threadIdx.x;
  if (i < n_edges) {
    int d, s;
    if (flag[0]) {
      d = ((const int2*)edges)[n_edges + i].x;
      s = ((const int2*)edges)[i].x;
    } else {
      d = edges[n_edges + i];
      s = edges[i];
    }
    if ((unsigned)d < (unsigned)n_nodes) {
      if ((unsigned)s >= (unsigned)n_nodes) s = 0;
      int pos = atomicAdd(&bcursor[d >> BSH], 1);
      packed[pos] = (s << BSH) | (d & (BSZ - 1));
    }
  }
}

// ---------- aggregation: one block per 16-node bucket ----------
// Phase 1 (lane-parallel): edge weights -> wbuf, wsum[16] via ds_add_f32.
// Phase 2 (one edge per wave): gather fp16 row, ds_add_f32 into acc[16][128].
__global__ __launch_bounds__(256) void k_bagg(
    const int* __restrict__ bstart, const int* __restrict__ packed,
    const float* __restrict__ s_from, const float* __restrict__ s_to,
    const __half* __restrict__ mh, int n_nodes, float* __restrict__ out) {
  __shared__ float acc[BSZ][DD];   // 8 KiB
  __shared__ float wbuf[CHK];      // 4 KiB
  __shared__ int   ibuf[CHK];      // 4 KiB
  __shared__ float wsum[BSZ];
  __shared__ float stl[BSZ];
  const int t = threadIdx.x;
  const int b = blockIdx.x;
  const int nbase = b << BSH;
  for (int i = t; i < BSZ * DD; i += 256) ((float*)acc)[i] = 0.f;
  if (t < BSZ) {
    wsum[t] = 0.f;
    int node = nbase + t;
    stl[t] = (node < n_nodes) ? s_to[node] : 0.f;
  }
  const int start = bstart[b], end = bstart[b + 1];
  __syncthreads();
  const int wave = t >> 6, lane = t & 63;
  for (int cb = start; cb < end; cb += CHK) {
    const int cn = min(CHK, end - cb);
    for (int i = t; i < cn; i += 256) {   // phase 1
      int u = packed[cb + i];
      int s = u >> BSH, dl = u & (BSZ - 1);
      float e = s_from[s] + stl[dl];
      e = (e >= 0.f) ? e : LEAKY * e;
      float w = __expf(e);   // no max-sub: softmax shift-invariant, e is O(1)
      wbuf[i] = w;
      ibuf[i] = u;
      atomicAdd(&wsum[dl], w);
    }
    __syncthreads();
    for (int i = wave; i < cn; i += 4) {  // phase 2
      int u = ibuf[i];
      float w = wbuf[i];
      int s = u >> BSH, dl = u & (BSZ - 1);
      float2 mf = __half22float2(((const __half2*)(mh + (size_t)s * DD))[lane]);
      atomicAdd(&acc[dl][2 * lane], w * mf.x);
      atomicAdd(&acc[dl][2 * lane + 1], w * mf.y);
    }
    __syncthreads();
  }
  for (int dl = wave; dl < BSZ; dl += 4) {  // epilogue: 4 rows per wave
    int node = nbase + dl;
    if (node >= n_nodes) break;
    float ws = wsum[dl];
    if (ws > 0.f) {
      float inv = 1.f / ws;
      float ax = acc[dl][2 * lane] * inv;
      float ay = acc[dl][2 * lane + 1] * inv;
      ax = ax > 0.f ? ax : 0.f;
      ay = ay > 0.f ? ay : 0.f;
      float2* orow = (float2*)(out + (size_t)node * DD);
      float2 po = orow[lane];   // passthrough written by k_msg
      orow[lane] = make_float2(po.x + ax, po.y + ay);
    }
  }
}

// ---------- host ----------
extern "C" void kernel_launch(void* const* d_in, const int* in_sizes, int n_in,
                              void* d_out, int out_size, void* d_ws, size_t ws_size,
                              hipStream_t stream) {
  const float* x = (const float*)d_in[0];
  const int* edges = (const int*)d_in[1];
  const float* Wm = (const float*)d_in[2];
  const float* aw = (const float*)d_in[3];
  const float* Wr = (const float*)d_in[4];
  const float* coef = (const float*)d_in[5];
  float* out = (float*)d_out;

  const int N = in_sizes[0] / DD;  // 100000
  const int E = in_sizes[1] / 2;   // 1600000
  const int nb = (N + BSZ - 1) / BSZ;  // 6250 buckets

  // Workspace budget check: never scribble past d_ws.
  const size_t need = ((size_t)N * DD * 2 + 256)       // mh (fp16 messages)
                    + 2 * ((size_t)N * 4 + 256)        // s_from, s_to
                    + 2 * ((size_t)DD * DD * 4 + 256)  // WTm, WTr
                    + 3 * ((size_t)(nb + 1) * 4 + 512) // bcnt, bstart, bcursor
                    + 1024                              // flags
                    + (size_t)E * 4 + 256;              // packed
  if (ws_size < need) return;  // refuse to run rather than corrupt memory

  char* w = (char*)d_ws;
  auto alloc = [&](size_t bytes) {
    char* p = w;
    w += (bytes + 255) & ~(size_t)255;
    return p;
  };
  __half* mh     = (__half*)alloc((size_t)N * DD * 2);
  float* s_from  = (float*)alloc((size_t)N * 4);
  float* s_to    = (float*)alloc((size_t)N * 4);
  float* WTm     = (float*)alloc((size_t)DD * DD * 4);
  float* WTr     = (float*)alloc((size_t)DD * DD * 4);
  int*   bcnt    = (int*)alloc((size_t)nb * 4);
  int*   bstart  = (int*)alloc((size_t)(nb + 1) * 4);
  int*   bcursor = (int*)alloc((size_t)nb * 4);
  int*   flag    = (int*)alloc(256);   // flag[0]=int64 layout, flag[1]=Wr==I
  int*   packed  = (int*)alloc((size_t)E * 4);

  k_detect<<<1, 64, 0, stream>>>(edges, flag);
  k_eye<<<1, 256, 0, stream>>>(Wr, flag + 1);
  k_transpose2<<<(DD * DD + 255) / 256, 256, 0, stream>>>(Wm, Wr, WTm, WTr);
  k_zero<<<(nb + 255) / 256, 256, 0, stream>>>(bcnt, nb);
  k_msg<<<(N + NPB - 1) / NPB, 256, 0, stream>>>(x, WTm, WTr, aw, coef, flag + 1,
                                                 N, mh, s_from, s_to, out);
  k_bcount<<<(E + 255) / 256, 256, 0, stream>>>(edges, E, N, flag, bcnt);
  k_bscan<<<1, 256, 0, stream>>>(bcnt, nb, bstart, bcursor);
  k_bscatter<<<(E + 255) / 256, 256, 0, stream>>>(edges, E, N, flag, bcursor, packed);
  k_bagg<<<nb, 256, 0, stream>>>(bstart, packed, s_from, s_to, mh, N, out);
}

// Round 6
// 494.687 us; speedup vs baseline: 2.8442x; 2.8442x over previous
//
#include <hip/hip_runtime.h>
#include <hip/hip_fp16.h>

// GAT layer: messages = X@Wm^T; e = lrelu(sf[src]+st[dst]); softmax over dst;
// merged = segsum(alpha * messages[src]); out = sig(c)*(X@Wr^T) + relu(merged).
//
// R5 post-mortem: LDS-atomic aggregation was 8x slower than register
// aggregation (242 GB/s, VALU 3.7%, occ 83% -> LDS RMW pipe serialization).
// R6: bucket partition kept (BSZ=8 -> 800 KB L2-resident scatter frontier,
// fixes R4's 16x write amplification), aggregation back to wave-owned
// REGISTER accumulators: one wave per 8-node bucket, shuffle-broadcast edges,
// wave-uniform scalar branch onto named accumulators. No atomics, no LDS.

#define DD 128
#define NPB 32           // nodes per block in the GEMM kernel
#define LEAKY 0.01f
#define BSH 3            // log2(nodes per bucket)
#define BSZ 8            // nodes per bucket

#define FMA4(A, XS, W)                                        \
  A.x = fmaf((XS), (W).x, A.x); A.y = fmaf((XS), (W).y, A.y); \
  A.z = fmaf((XS), (W).z, A.z); A.w = fmaf((XS), (W).w, A.w)

// ---------- tiny helpers ----------
__global__ void k_transpose2(const float* __restrict__ Wm, const float* __restrict__ Wr,
                             float* __restrict__ WTm, float* __restrict__ WTr) {
  int idx = blockIdx.x * blockDim.x + threadIdx.x;
  if (idx < DD * DD) {
    int j = idx >> 7, k = idx & (DD - 1);
    WTm[k * DD + j] = Wm[idx];   // WT[k][j] = W[j][k]
    WTr[k * DD + j] = Wr[idx];
  }
}

__global__ void k_zero(int* __restrict__ p, int n) {
  int i = blockIdx.x * blockDim.x + threadIdx.x;
  if (i < n) p[i] = 0;
}

// Detect whether the edges buffer is int64 (odd int32 words all zero) or int32.
__global__ void k_detect(const int* __restrict__ e, int* __restrict__ flag) {
  if (threadIdx.x == 0 && blockIdx.x == 0) {
    int all0 = 1;
    for (int i = 0; i < 64; ++i)
      if (e[2 * i + 1] != 0) { all0 = 0; break; }
    flag[0] = all0;  // 1 -> int64 layout
  }
}

// Exact check: is W_res the identity? (one block, 256 threads)
__global__ void k_eye(const float* __restrict__ Wr, int* __restrict__ eyeflag) {
  __shared__ int ok_s;
  if (threadIdx.x == 0) ok_s = 1;
  __syncthreads();
  int ok = 1;
  for (int i = threadIdx.x; i < DD * DD; i += 256) {
    float expect = ((i >> 7) == (i & (DD - 1))) ? 1.f : 0.f;
    if (Wr[i] != expect) ok = 0;
  }
  if (!ok) ok_s = 0;  // benign race: all writers write 0
  __syncthreads();
  if (threadIdx.x == 0) eyeflag[0] = ok_s;
}

// ---------- fused GEMM: messages + scores + passthrough ----------
__global__ __launch_bounds__(256) void k_msg(
    const float* __restrict__ x, const float* __restrict__ WTm,
    const float* __restrict__ WTr, const float* __restrict__ attn_w,
    const float* __restrict__ coef, const int* __restrict__ eyeflag, int n_nodes,
    __half* __restrict__ mh, float* __restrict__ s_from,
    float* __restrict__ s_to, float* __restrict__ out) {
  __shared__ float4 lw4[32 * 32];    // one chunk: 32 k-rows x 32 float4-cols, 16 KiB
  __shared__ float4 lx4[NPB * 32];   // 32 node rows x 32 float4, 16 KiB
  __shared__ float lds_aw[2 * DD];   // 1 KiB
  const int t = threadIdx.x;
  const int base = blockIdx.x * NPB;
  const int nvalid = min(NPB, n_nodes - base);

  // stage X rows (flat copy, coalesced float4)
  const float4* xs = (const float4*)(x + (size_t)base * DD);
  const int nflt4 = nvalid * 32;
  for (int i = t; i < nflt4; i += 256) lx4[i] = xs[i];
  if (t < 2 * DD) lds_aw[t] = attn_w[t];

  const int j4 = t & 31;   // float4-column (outputs 4*j4..4*j4+3)
  const int g = t >> 5;    // node group (half-wave uniform)
  const int r0 = (g * 4 + 0) * 32, r1 = r0 + 32, r2 = r1 + 32, r3 = r2 + 32;

  float4 a0, a1, a2, a3;

  // Named accumulators, bounded unroll -> no spill (R1 lesson: full unroll
  // hit 256 VGPR + 6.4 GB scratch traffic).
#define GEMM128(WT)                                                           \
  a0 = a1 = a2 = a3 = make_float4(0.f, 0.f, 0.f, 0.f);                        \
  _Pragma("unroll 1")                                                         \
  for (int chunk = 0; chunk < 4; ++chunk) {                                   \
    __syncthreads();                                                          \
    const float4* wsrc = (const float4*)((WT) + chunk * 32 * DD);             \
    lw4[t] = wsrc[t];                                                         \
    lw4[t + 256] = wsrc[t + 256];                                             \
    lw4[t + 512] = wsrc[t + 512];                                             \
    lw4[t + 768] = wsrc[t + 768];                                             \
    __syncthreads();                                                          \
    const int xb = chunk * 8;                                                 \
    _Pragma("unroll 2")                                                       \
    for (int k = 0; k < 32; k += 4) {                                         \
      float4 w0 = lw4[(k + 0) * 32 + j4];                                     \
      float4 w1 = lw4[(k + 1) * 32 + j4];                                     \
      float4 w2 = lw4[(k + 2) * 32 + j4];                                     \
      float4 w3 = lw4[(k + 3) * 32 + j4];                                     \
      float4 x0 = lx4[r0 + xb + (k >> 2)];                                    \
      float4 x1 = lx4[r1 + xb + (k >> 2)];                                    \
      float4 x2 = lx4[r2 + xb + (k >> 2)];                                    \
      float4 x3 = lx4[r3 + xb + (k >> 2)];                                    \
      FMA4(a0, x0.x, w0); FMA4(a0, x0.y, w1);                                 \
      FMA4(a0, x0.z, w2); FMA4(a0, x0.w, w3);                                 \
      FMA4(a1, x1.x, w0); FMA4(a1, x1.y, w1);                                 \
      FMA4(a1, x1.z, w2); FMA4(a1, x1.w, w3);                                 \
      FMA4(a2, x2.x, w0); FMA4(a2, x2.y, w1);                                 \
      FMA4(a2, x2.z, w2); FMA4(a2, x2.w, w3);                                 \
      FMA4(a3, x3.x, w0); FMA4(a3, x3.y, w1);                                 \
      FMA4(a3, x3.z, w2); FMA4(a3, x3.w, w3);                                 \
    }                                                                         \
  }

  // ---- phase A: messages = X @ Wm^T (fp16 store), plus attention scores ----
  GEMM128(WTm);
  {
    float4 av[4] = {a0, a1, a2, a3};
#pragma unroll
    for (int b = 0; b < 4; ++b) {
      int n = g * 4 + b;
      if (n < nvalid) {   // uniform across the 32-lane group
        int gn = base + n;
        float4 v = av[b];
        union { __half2 h2[2]; uint2 u; } pk;
        pk.h2[0] = __floats2half2_rn(v.x, v.y);
        pk.h2[1] = __floats2half2_rn(v.z, v.w);
        ((uint2*)(mh + (size_t)gn * DD))[j4] = pk.u;
        float sf = v.x * lds_aw[4 * j4] + v.y * lds_aw[4 * j4 + 1] +
                   v.z * lds_aw[4 * j4 + 2] + v.w * lds_aw[4 * j4 + 3];
        float stv = v.x * lds_aw[DD + 4 * j4] + v.y * lds_aw[DD + 4 * j4 + 1] +
                    v.z * lds_aw[DD + 4 * j4 + 2] + v.w * lds_aw[DD + 4 * j4 + 3];
#pragma unroll
        for (int m = 16; m; m >>= 1) {
          sf += __shfl_xor(sf, m, 32);
          stv += __shfl_xor(stv, m, 32);
        }
        if (j4 == 0) { s_from[gn] = sf; s_to[gn] = stv; }
      }
    }
  }

  // ---- phase B: passthrough = sig(c) * (X @ Wr^T) -> d_out ----
  const float sig = 1.f / (1.f + __expf(-coef[0]));
  if (eyeflag[0]) {
    // W_res == I (the reference init): passthrough = sig * x. lds_x intact.
    float4* od = (float4*)(out + (size_t)base * DD);
    for (int i = t; i < nflt4; i += 256) {
      float4 v = lx4[i];
      v.x *= sig; v.y *= sig; v.z *= sig; v.w *= sig;
      od[i] = v;
    }
  } else {
    GEMM128(WTr);
    float4 av[4] = {a0, a1, a2, a3};
#pragma unroll
    for (int b = 0; b < 4; ++b) {
      int n = g * 4 + b;
      if (n < nvalid) {
        int gn = base + n;
        float4 v = av[b];
        v.x *= sig; v.y *= sig; v.z *= sig; v.w *= sig;
        ((float4*)(out + (size_t)gn * DD))[j4] = v;
      }
    }
  }
#undef GEMM128
}

// ---------- bucket partition (dst >> BSH) ----------
__global__ void k_bcount(const int* __restrict__ edges, int n_edges, int n_nodes,
                         const int* __restrict__ flag, int* __restrict__ bcnt) {
  int i = blockIdx.x * blockDim.x + threadIdx.x;
  if (i < n_edges) {
    int d = flag[0] ? ((const int2*)edges)[n_edges + i].x : edges[n_edges + i];
    if ((unsigned)d < (unsigned)n_nodes) atomicAdd(&bcnt[d >> BSH], 1);
  }
}

// Single-block scan over nb buckets, chunked 1024 at a time.
__global__ __launch_bounds__(256) void k_bscan(const int* __restrict__ cnt, int nb,
                                               int* __restrict__ bstart,
                                               int* __restrict__ bcursor) {
  __shared__ int lds[256];
  __shared__ int carry_s;
  const int t = threadIdx.x;
  if (t == 0) carry_s = 0;
  __syncthreads();
  const int nchunks = (nb + 1023) / 1024;
  for (int c = 0; c < nchunks; ++c) {
    const int carry = carry_s;
    const int base = c * 1024 + t * 4;
    int v0 = 0, v1 = 0, v2 = 0, v3 = 0;
    if (base + 0 < nb) v0 = cnt[base + 0];
    if (base + 1 < nb) v1 = cnt[base + 1];
    if (base + 2 < nb) v2 = cnt[base + 2];
    if (base + 3 < nb) v3 = cnt[base + 3];
    const int tsum = v0 + v1 + v2 + v3;
    int val = tsum;
    lds[t] = val;
    __syncthreads();
    for (int off = 1; off < 256; off <<= 1) {
      int a = (t >= off) ? lds[t - off] : 0;
      __syncthreads();
      val += a;
      lds[t] = val;
      __syncthreads();
    }
    int o0 = carry + val - tsum;
    int o1 = o0 + v0, o2 = o1 + v1, o3 = o2 + v2;
    if (base + 0 < nb) { bstart[base + 0] = o0; bcursor[base + 0] = o0; }
    if (base + 1 < nb) { bstart[base + 1] = o1; bcursor[base + 1] = o1; }
    if (base + 2 < nb) { bstart[base + 2] = o2; bcursor[base + 2] = o2; }
    if (base + 3 < nb) { bstart[base + 3] = o3; bcursor[base + 3] = o3; }
    __syncthreads();
    if (t == 255) carry_s = carry + val;
    __syncthreads();
  }
  if (t == 0) bstart[nb] = carry_s;
}

// Scatter packed (src<<BSH | dst&7) into bucket-contiguous regions.
// Write frontier = nb lines = 800 KB -> L2-resident (R4's 6.4 MB thrashed,
// R5's 400 KB was clean).
__global__ void k_bscatter(const int* __restrict__ edges, int n_edges, int n_nodes,
                           const int* __restrict__ flag, int* __restrict__ bcursor,
                           int* __restrict__ packed) {
  int i = blockIdx.x * blockDim.x + threadIdx.x;
  if (i < n_edges) {
    int d, s;
    if (flag[0]) {
      d = ((const int2*)edges)[n_edges + i].x;
      s = ((const int2*)edges)[i].x;
    } else {
      d = edges[n_edges + i];
      s = edges[i];
    }
    if ((unsigned)d < (unsigned)n_nodes) {
      if ((unsigned)s >= (unsigned)n_nodes) s = 0;
      int pos = atomicAdd(&bcursor[d >> BSH], 1);
      packed[pos] = (s << BSH) | (d & (BSZ - 1));
    }
  }
}

// ---------- aggregation: one wave per 8-node bucket, register accumulators ----
// Per 64-edge batch: lane-parallel weight compute (s_from gather, ~full lanes
// since avg bucket = 128 edges), then shuffle-broadcast each edge; dst-lane is
// wave-uniform (readfirstlane) -> scalar branch onto NAMED accumulators
// (runtime-indexed arrays would spill to scratch). No atomics, no LDS.
__global__ __launch_bounds__(256) void k_wagg(
    const int* __restrict__ bstart, const int* __restrict__ packed,
    const float* __restrict__ s_from, const float* __restrict__ s_to,
    const __half* __restrict__ mh, int n_nodes, int nb, float* __restrict__ out) {
  const int lane = threadIdx.x & 63;
  const int b = blockIdx.x * 4 + (threadIdx.x >> 6);
  if (b >= nb) return;
  const int start = bstart[b], end = bstart[b + 1];
  if (start >= end) return;
  const int nbase = b << BSH;

  float ws0 = 0.f, ax0 = 0.f, ay0 = 0.f;
  float ws1 = 0.f, ax1 = 0.f, ay1 = 0.f;
  float ws2 = 0.f, ax2 = 0.f, ay2 = 0.f;
  float ws3 = 0.f, ax3 = 0.f, ay3 = 0.f;
  float ws4 = 0.f, ax4 = 0.f, ay4 = 0.f;
  float ws5 = 0.f, ax5 = 0.f, ay5 = 0.f;
  float ws6 = 0.f, ax6 = 0.f, ay6 = 0.f;
  float ws7 = 0.f, ax7 = 0.f, ay7 = 0.f;

  for (int cb = start; cb < end; cb += 64) {
    const int cnt = min(64, end - cb);
    int u = 0;
    float wv = 0.f;
    if (lane < cnt) {
      u = packed[cb + lane];
      int s = u >> BSH;
      float e = s_from[s] + s_to[nbase + (u & (BSZ - 1))];
      e = (e >= 0.f) ? e : LEAKY * e;
      wv = __expf(e);  // no max-sub: softmax shift-invariant, e is O(1)
    }
#pragma unroll 4
    for (int i = 0; i < cnt; ++i) {
      int ui = __shfl(u, i, 64);
      float wi = __shfl(wv, i, 64);
      const float2 mf =
          __half22float2(((const __half2*)(mh + (size_t)(ui >> BSH) * DD))[lane]);
      const int dl = __builtin_amdgcn_readfirstlane(ui) & (BSZ - 1);
      if (dl == 0)      { ws0 += wi; ax0 = fmaf(wi, mf.x, ax0); ay0 = fmaf(wi, mf.y, ay0); }
      else if (dl == 1) { ws1 += wi; ax1 = fmaf(wi, mf.x, ax1); ay1 = fmaf(wi, mf.y, ay1); }
      else if (dl == 2) { ws2 += wi; ax2 = fmaf(wi, mf.x, ax2); ay2 = fmaf(wi, mf.y, ay2); }
      else if (dl == 3) { ws3 += wi; ax3 = fmaf(wi, mf.x, ax3); ay3 = fmaf(wi, mf.y, ay3); }
      else if (dl == 4) { ws4 += wi; ax4 = fmaf(wi, mf.x, ax4); ay4 = fmaf(wi, mf.y, ay4); }
      else if (dl == 5) { ws5 += wi; ax5 = fmaf(wi, mf.x, ax5); ay5 = fmaf(wi, mf.y, ay5); }
      else if (dl == 6) { ws6 += wi; ax6 = fmaf(wi, mf.x, ax6); ay6 = fmaf(wi, mf.y, ay6); }
      else              { ws7 += wi; ax7 = fmaf(wi, mf.x, ax7); ay7 = fmaf(wi, mf.y, ay7); }
    }
  }

  // epilogue: normalize + relu + RMW the output row (passthrough from k_msg)
#define EPI(K)                                                                \
  {                                                                           \
    int node = nbase + K;                                                     \
    if (node < n_nodes && ws##K > 0.f) {                                      \
      float inv = 1.f / ws##K;                                                \
      float axx = ax##K * inv, ayy = ay##K * inv;                             \
      axx = axx > 0.f ? axx : 0.f;                                            \
      ayy = ayy > 0.f ? ayy : 0.f;                                            \
      float2* orow = (float2*)(out + (size_t)node * DD);                      \
      float2 po = orow[lane];                                                 \
      orow[lane] = make_float2(po.x + axx, po.y + ayy);                       \
    }                                                                         \
  }
  EPI(0) EPI(1) EPI(2) EPI(3) EPI(4) EPI(5) EPI(6) EPI(7)
#undef EPI
}

// ---------- host ----------
extern "C" void kernel_launch(void* const* d_in, const int* in_sizes, int n_in,
                              void* d_out, int out_size, void* d_ws, size_t ws_size,
                              hipStream_t stream) {
  const float* x = (const float*)d_in[0];
  const int* edges = (const int*)d_in[1];
  const float* Wm = (const float*)d_in[2];
  const float* aw = (const float*)d_in[3];
  const float* Wr = (const float*)d_in[4];
  const float* coef = (const float*)d_in[5];
  float* out = (float*)d_out;

  const int N = in_sizes[0] / DD;  // 100000
  const int E = in_sizes[1] / 2;   // 1600000
  const int nb = (N + BSZ - 1) / BSZ;  // 12500 buckets

  // Workspace budget check: never scribble past d_ws.
  const size_t need = ((size_t)N * DD * 2 + 256)       // mh (fp16 messages)
                    + 2 * ((size_t)N * 4 + 256)        // s_from, s_to
                    + 2 * ((size_t)DD * DD * 4 + 256)  // WTm, WTr
                    + 3 * ((size_t)(nb + 1) * 4 + 512) // bcnt, bstart, bcursor
                    + 1024                              // flags
                    + (size_t)E * 4 + 256;              // packed
  if (ws_size < need) return;  // refuse to run rather than corrupt memory

  char* w = (char*)d_ws;
  auto alloc = [&](size_t bytes) {
    char* p = w;
    w += (bytes + 255) & ~(size_t)255;
    return p;
  };
  __half* mh     = (__half*)alloc((size_t)N * DD * 2);
  float* s_from  = (float*)alloc((size_t)N * 4);
  float* s_to    = (float*)alloc((size_t)N * 4);
  float* WTm     = (float*)alloc((size_t)DD * DD * 4);
  float* WTr     = (float*)alloc((size_t)DD * DD * 4);
  int*   bcnt    = (int*)alloc((size_t)nb * 4);
  int*   bstart  = (int*)alloc((size_t)(nb + 1) * 4);
  int*   bcursor = (int*)alloc((size_t)nb * 4);
  int*   flag    = (int*)alloc(256);   // flag[0]=int64 layout, flag[1]=Wr==I
  int*   packed  = (int*)alloc((size_t)E * 4);

  k_detect<<<1, 64, 0, stream>>>(edges, flag);
  k_eye<<<1, 256, 0, stream>>>(Wr, flag + 1);
  k_transpose2<<<(DD * DD + 255) / 256, 256, 0, stream>>>(Wm, Wr, WTm, WTr);
  k_zero<<<(nb + 255) / 256, 256, 0, stream>>>(bcnt, nb);
  k_msg<<<(N + NPB - 1) / NPB, 256, 0, stream>>>(x, WTm, WTr, aw, coef, flag + 1,
                                                 N, mh, s_from, s_to, out);
  k_bcount<<<(E + 255) / 256, 256, 0, stream>>>(edges, E, N, flag, bcnt);
  k_bscan<<<1, 256, 0, stream>>>(bcnt, nb, bstart, bcursor);
  k_bscatter<<<(E + 255) / 256, 256, 0, stream>>>(edges, E, N, flag, bcursor, packed);
  k_wagg<<<(nb + 3) / 4, 256, 0, stream>>>(bstart, packed, s_from, s_to,
                                           mh, N, nb, out);
}

// Round 8
// 476.734 us; speedup vs baseline: 2.9513x; 1.0377x over previous
//
#include <hip/hip_runtime.h>
#include <hip/hip_fp16.h>

// GAT layer: messages = X@Wm^T; e = lrelu(sf[src]+st[dst]); softmax over dst;
// merged = segsum(alpha * messages[src]); out = sig(c)*(X@Wr^T) + relu(merged).
//
// R6 post-mortem: k_wagg's per-edge 8-way scalar branch chain defeated load
// pipelining (VALU 43%, BW 22% -> latency-bound). R7 (resubmitted after
// broker timeout): branch-free again. Bucket-8 scatter kept (L2-resident
// frontier, proven), k_bsort counting-sorts each bucket's contiguous range
// into node order (ballot/popc ranks, all I/O bucket-contiguous) and emits
// row_start. k_nagg = wave per node, 2-VGPR accumulators, unconditional FMA
// body, unroll 8 -> loads in flight.

#define DD 128
#define NPB 32           // nodes per block in the GEMM kernel
#define LEAKY 0.01f
#define BSH 3            // log2(nodes per bucket)
#define BSZ 8            // nodes per bucket

#define FMA4(A, XS, W)                                        \
  A.x = fmaf((XS), (W).x, A.x); A.y = fmaf((XS), (W).y, A.y); \
  A.z = fmaf((XS), (W).z, A.z); A.w = fmaf((XS), (W).w, A.w)

// ---------- tiny helpers ----------
__global__ void k_transpose2(const float* __restrict__ Wm, const float* __restrict__ Wr,
                             float* __restrict__ WTm, float* __restrict__ WTr) {
  int idx = blockIdx.x * blockDim.x + threadIdx.x;
  if (idx < DD * DD) {
    int j = idx >> 7, k = idx & (DD - 1);
    WTm[k * DD + j] = Wm[idx];   // WT[k][j] = W[j][k]
    WTr[k * DD + j] = Wr[idx];
  }
}

__global__ void k_zero(int* __restrict__ p, int n) {
  int i = blockIdx.x * blockDim.x + threadIdx.x;
  if (i < n) p[i] = 0;
}

// Detect whether the edges buffer is int64 (odd int32 words all zero) or int32.
__global__ void k_detect(const int* __restrict__ e, int* __restrict__ flag) {
  if (threadIdx.x == 0 && blockIdx.x == 0) {
    int all0 = 1;
    for (int i = 0; i < 64; ++i)
      if (e[2 * i + 1] != 0) { all0 = 0; break; }
    flag[0] = all0;  // 1 -> int64 layout
  }
}

// Exact check: is W_res the identity? (one block, 256 threads)
__global__ void k_eye(const float* __restrict__ Wr, int* __restrict__ eyeflag) {
  __shared__ int ok_s;
  if (threadIdx.x == 0) ok_s = 1;
  __syncthreads();
  int ok = 1;
  for (int i = threadIdx.x; i < DD * DD; i += 256) {
    float expect = ((i >> 7) == (i & (DD - 1))) ? 1.f : 0.f;
    if (Wr[i] != expect) ok = 0;
  }
  if (!ok) ok_s = 0;  // benign race: all writers write 0
  __syncthreads();
  if (threadIdx.x == 0) eyeflag[0] = ok_s;
}

// ---------- fused GEMM: messages + scores + passthrough ----------
__global__ __launch_bounds__(256) void k_msg(
    const float* __restrict__ x, const float* __restrict__ WTm,
    const float* __restrict__ WTr, const float* __restrict__ attn_w,
    const float* __restrict__ coef, const int* __restrict__ eyeflag, int n_nodes,
    __half* __restrict__ mh, float* __restrict__ s_from,
    float* __restrict__ s_to, float* __restrict__ out) {
  __shared__ float4 lw4[32 * 32];    // one chunk: 32 k-rows x 32 float4-cols, 16 KiB
  __shared__ float4 lx4[NPB * 32];   // 32 node rows x 32 float4, 16 KiB
  __shared__ float lds_aw[2 * DD];   // 1 KiB
  const int t = threadIdx.x;
  const int base = blockIdx.x * NPB;
  const int nvalid = min(NPB, n_nodes - base);

  // stage X rows (flat copy, coalesced float4)
  const float4* xs = (const float4*)(x + (size_t)base * DD);
  const int nflt4 = nvalid * 32;
  for (int i = t; i < nflt4; i += 256) lx4[i] = xs[i];
  if (t < 2 * DD) lds_aw[t] = attn_w[t];

  const int j4 = t & 31;   // float4-column (outputs 4*j4..4*j4+3)
  const int g = t >> 5;    // node group (half-wave uniform)
  const int r0 = (g * 4 + 0) * 32, r1 = r0 + 32, r2 = r1 + 32, r3 = r2 + 32;

  float4 a0, a1, a2, a3;

  // Named accumulators, bounded unroll -> no spill (R1 lesson: full unroll
  // hit 256 VGPR + 6.4 GB scratch traffic).
#define GEMM128(WT)                                                           \
  a0 = a1 = a2 = a3 = make_float4(0.f, 0.f, 0.f, 0.f);                        \
  _Pragma("unroll 1")                                                         \
  for (int chunk = 0; chunk < 4; ++chunk) {                                   \
    __syncthreads();                                                          \
    const float4* wsrc = (const float4*)((WT) + chunk * 32 * DD);             \
    lw4[t] = wsrc[t];                                                         \
    lw4[t + 256] = wsrc[t + 256];                                             \
    lw4[t + 512] = wsrc[t + 512];                                             \
    lw4[t + 768] = wsrc[t + 768];                                             \
    __syncthreads();                                                          \
    const int xb = chunk * 8;                                                 \
    _Pragma("unroll 2")                                                       \
    for (int k = 0; k < 32; k += 4) {                                         \
      float4 w0 = lw4[(k + 0) * 32 + j4];                                     \
      float4 w1 = lw4[(k + 1) * 32 + j4];                                     \
      float4 w2 = lw4[(k + 2) * 32 + j4];                                     \
      float4 w3 = lw4[(k + 3) * 32 + j4];                                     \
      float4 x0 = lx4[r0 + xb + (k >> 2)];                                    \
      float4 x1 = lx4[r1 + xb + (k >> 2)];                                    \
      float4 x2 = lx4[r2 + xb + (k >> 2)];                                    \
      float4 x3 = lx4[r3 + xb + (k >> 2)];                                    \
      FMA4(a0, x0.x, w0); FMA4(a0, x0.y, w1);                                 \
      FMA4(a0, x0.z, w2); FMA4(a0, x0.w, w3);                                 \
      FMA4(a1, x1.x, w0); FMA4(a1, x1.y, w1);                                 \
      FMA4(a1, x1.z, w2); FMA4(a1, x1.w, w3);                                 \
      FMA4(a2, x2.x, w0); FMA4(a2, x2.y, w1);                                 \
      FMA4(a2, x2.z, w2); FMA4(a2, x2.w, w3);                                 \
      FMA4(a3, x3.x, w0); FMA4(a3, x3.y, w1);                                 \
      FMA4(a3, x3.z, w2); FMA4(a3, x3.w, w3);                                 \
    }                                                                         \
  }

  // ---- phase A: messages = X @ Wm^T (fp16 store), plus attention scores ----
  GEMM128(WTm);
  {
    float4 av[4] = {a0, a1, a2, a3};
#pragma unroll
    for (int b = 0; b < 4; ++b) {
      int n = g * 4 + b;
      if (n < nvalid) {   // uniform across the 32-lane group
        int gn = base + n;
        float4 v = av[b];
        union { __half2 h2[2]; uint2 u; } pk;
        pk.h2[0] = __floats2half2_rn(v.x, v.y);
        pk.h2[1] = __floats2half2_rn(v.z, v.w);
        ((uint2*)(mh + (size_t)gn * DD))[j4] = pk.u;
        float sf = v.x * lds_aw[4 * j4] + v.y * lds_aw[4 * j4 + 1] +
                   v.z * lds_aw[4 * j4 + 2] + v.w * lds_aw[4 * j4 + 3];
        float stv = v.x * lds_aw[DD + 4 * j4] + v.y * lds_aw[DD + 4 * j4 + 1] +
                    v.z * lds_aw[DD + 4 * j4 + 2] + v.w * lds_aw[DD + 4 * j4 + 3];
#pragma unroll
        for (int m = 16; m; m >>= 1) {
          sf += __shfl_xor(sf, m, 32);
          stv += __shfl_xor(stv, m, 32);
        }
        if (j4 == 0) { s_from[gn] = sf; s_to[gn] = stv; }
      }
    }
  }

  // ---- phase B: passthrough = sig(c) * (X @ Wr^T) -> d_out ----
  const float sig = 1.f / (1.f + __expf(-coef[0]));
  if (eyeflag[0]) {
    // W_res == I (the reference init): passthrough = sig * x. lds_x intact.
    float4* od = (float4*)(out + (size_t)base * DD);
    for (int i = t; i < nflt4; i += 256) {
      float4 v = lx4[i];
      v.x *= sig; v.y *= sig; v.z *= sig; v.w *= sig;
      od[i] = v;
    }
  } else {
    GEMM128(WTr);
    float4 av[4] = {a0, a1, a2, a3};
#pragma unroll
    for (int b = 0; b < 4; ++b) {
      int n = g * 4 + b;
      if (n < nvalid) {
        int gn = base + n;
        float4 v = av[b];
        v.x *= sig; v.y *= sig; v.z *= sig; v.w *= sig;
        ((float4*)(out + (size_t)gn * DD))[j4] = v;
      }
    }
  }
#undef GEMM128
}

// ---------- bucket partition (dst >> BSH) ----------
__global__ void k_bcount(const int* __restrict__ edges, int n_edges, int n_nodes,
                         const int* __restrict__ flag, int* __restrict__ bcnt) {
  int i = blockIdx.x * blockDim.x + threadIdx.x;
  if (i < n_edges) {
    int d = flag[0] ? ((const int2*)edges)[n_edges + i].x : edges[n_edges + i];
    if ((unsigned)d < (unsigned)n_nodes) atomicAdd(&bcnt[d >> BSH], 1);
  }
}

// Single-block scan over nb buckets, chunked 1024 at a time.
__global__ __launch_bounds__(256) void k_bscan(const int* __restrict__ cnt, int nb,
                                               int* __restrict__ bstart,
                                               int* __restrict__ bcursor) {
  __shared__ int lds[256];
  __shared__ int carry_s;
  const int t = threadIdx.x;
  if (t == 0) carry_s = 0;
  __syncthreads();
  const int nchunks = (nb + 1023) / 1024;
  for (int c = 0; c < nchunks; ++c) {
    const int carry = carry_s;
    const int base = c * 1024 + t * 4;
    int v0 = 0, v1 = 0, v2 = 0, v3 = 0;
    if (base + 0 < nb) v0 = cnt[base + 0];
    if (base + 1 < nb) v1 = cnt[base + 1];
    if (base + 2 < nb) v2 = cnt[base + 2];
    if (base + 3 < nb) v3 = cnt[base + 3];
    const int tsum = v0 + v1 + v2 + v3;
    int val = tsum;
    lds[t] = val;
    __syncthreads();
    for (int off = 1; off < 256; off <<= 1) {
      int a = (t >= off) ? lds[t - off] : 0;
      __syncthreads();
      val += a;
      lds[t] = val;
      __syncthreads();
    }
    int o0 = carry + val - tsum;
    int o1 = o0 + v0, o2 = o1 + v1, o3 = o2 + v2;
    if (base + 0 < nb) { bstart[base + 0] = o0; bcursor[base + 0] = o0; }
    if (base + 1 < nb) { bstart[base + 1] = o1; bcursor[base + 1] = o1; }
    if (base + 2 < nb) { bstart[base + 2] = o2; bcursor[base + 2] = o2; }
    if (base + 3 < nb) { bstart[base + 3] = o3; bcursor[base + 3] = o3; }
    __syncthreads();
    if (t == 255) carry_s = carry + val;
    __syncthreads();
  }
  if (t == 0) bstart[nb] = carry_s;
}

// Scatter packed (src<<BSH | dst&7) into bucket-contiguous regions.
// Write frontier = nb lines = 800 KB -> L2-resident.
__global__ void k_bscatter(const int* __restrict__ edges, int n_edges, int n_nodes,
                           const int* __restrict__ flag, int* __restrict__ bcursor,
                           int* __restrict__ packed) {
  int i = blockIdx.x * blockDim.x + threadIdx.x;
  if (i < n_edges) {
    int d, s;
    if (flag[0]) {
      d = ((const int2*)edges)[n_edges + i].x;
      s = ((const int2*)edges)[i].x;
    } else {
      d = edges[n_edges + i];
      s = edges[i];
    }
    if ((unsigned)d < (unsigned)n_nodes) {
      if ((unsigned)s >= (unsigned)n_nodes) s = 0;
      int pos = atomicAdd(&bcursor[d >> BSH], 1);
      packed[pos] = (s << BSH) | (d & (BSZ - 1));
    }
  }
}

// ---------- within-bucket counting sort -> node-sorted CSR ----------
// One wave per bucket. All reads/writes hit the bucket's own contiguous
// ~(deg*4 B) range -> no scatter amplification. Emits row_start for free.
__global__ __launch_bounds__(256) void k_bsort(
    const int* __restrict__ bstart, const int* __restrict__ packed,
    int nb, int n_nodes, int n_edges_total,
    int* __restrict__ srcs, int* __restrict__ row_start) {
  const int lane = threadIdx.x & 63;
  const int b = blockIdx.x * 4 + (threadIdx.x >> 6);
  if (b >= nb) return;
  const int start = bstart[b], end = bstart[b + 1];
  const int nbase = b << BSH;
  if (b == 0 && lane == 0) row_start[n_nodes] = n_edges_total;

  // pass 1: per-dl counts via ballots (wave-uniform)
  int c0 = 0, c1 = 0, c2 = 0, c3 = 0, c4 = 0, c5 = 0, c6 = 0, c7 = 0;
  for (int cb = start; cb < end; cb += 64) {
    const bool act = (cb + lane) < end;
    const int u = act ? packed[cb + lane] : 0;
    const int dl = u & (BSZ - 1);
    const unsigned long long b0 = __ballot(act && (dl & 1));
    const unsigned long long b1 = __ballot(act && (dl & 2));
    const unsigned long long b2 = __ballot(act && (dl & 4));
    const unsigned long long ba = __ballot(act);
    c0 += __popcll(~b0 & ~b1 & ~b2 & ba);
    c1 += __popcll( b0 & ~b1 & ~b2 & ba);
    c2 += __popcll(~b0 &  b1 & ~b2 & ba);
    c3 += __popcll( b0 &  b1 & ~b2 & ba);
    c4 += __popcll(~b0 & ~b1 &  b2 & ba);
    c5 += __popcll( b0 & ~b1 &  b2 & ba);
    c6 += __popcll(~b0 &  b1 &  b2 & ba);
    c7 += __popcll( b0 &  b1 &  b2 & ba);
  }
  // exclusive prefix over the 8 keys (uniform scalars)
  const int o0 = 0, o1 = o0 + c0, o2 = o1 + c1, o3 = o2 + c2, o4 = o3 + c3,
            o5 = o4 + c4, o6 = o5 + c5, o7 = o6 + c6;
  if (lane == 0) {
    // contiguous row_start writes for this bucket's 8 nodes
    if (nbase + 0 < n_nodes) row_start[nbase + 0] = start + o0;
    if (nbase + 1 < n_nodes) row_start[nbase + 1] = start + o1;
    if (nbase + 2 < n_nodes) row_start[nbase + 2] = start + o2;
    if (nbase + 3 < n_nodes) row_start[nbase + 3] = start + o3;
    if (nbase + 4 < n_nodes) row_start[nbase + 4] = start + o4;
    if (nbase + 5 < n_nodes) row_start[nbase + 5] = start + o5;
    if (nbase + 6 < n_nodes) row_start[nbase + 6] = start + o6;
    if (nbase + 7 < n_nodes) row_start[nbase + 7] = start + o7;
  }
  // pass 2: stable scatter within the bucket (running cursors per key)
  int r0 = o0, r1 = o1, r2 = o2, r3 = o3, r4 = o4, r5 = o5, r6 = o6, r7 = o7;
  for (int cb = start; cb < end; cb += 64) {
    const bool act = (cb + lane) < end;
    const int u = act ? packed[cb + lane] : 0;
    const int dl = u & (BSZ - 1);
    const unsigned long long b0 = __ballot(act && (dl & 1));
    const unsigned long long b1 = __ballot(act && (dl & 2));
    const unsigned long long b2 = __ballot(act && (dl & 4));
    const unsigned long long ba = __ballot(act);
    // my key's mask (per-lane), rank among same-key lanes below me
    const unsigned long long m0 = (dl & 1) ? b0 : ~b0;
    const unsigned long long m1 = (dl & 2) ? b1 : ~b1;
    const unsigned long long m2 = (dl & 4) ? b2 : ~b2;
    const unsigned long long mymask = m0 & m1 & m2 & ba;
    const int rank = __popcll(mymask & ((1ull << lane) - 1ull));
    int basep = r0;
    basep = (dl == 1) ? r1 : basep;
    basep = (dl == 2) ? r2 : basep;
    basep = (dl == 3) ? r3 : basep;
    basep = (dl == 4) ? r4 : basep;
    basep = (dl == 5) ? r5 : basep;
    basep = (dl == 6) ? r6 : basep;
    basep = (dl == 7) ? r7 : basep;
    if (act) srcs[start + basep + rank] = u >> BSH;
    r0 += __popcll(~b0 & ~b1 & ~b2 & ba);
    r1 += __popcll( b0 & ~b1 & ~b2 & ba);
    r2 += __popcll(~b0 &  b1 & ~b2 & ba);
    r3 += __popcll( b0 &  b1 & ~b2 & ba);
    r4 += __popcll(~b0 & ~b1 &  b2 & ba);
    r5 += __popcll( b0 & ~b1 &  b2 & ba);
    r6 += __popcll(~b0 &  b1 &  b2 & ba);
    r7 += __popcll( b0 &  b1 &  b2 & ba);
  }
}

// ---------- aggregation: one wave per node, branch-free, fp16 gather ----------
__global__ __launch_bounds__(256) void k_nagg(
    const int* __restrict__ row_start, const int* __restrict__ srcs,
    const float* __restrict__ s_from, const float* __restrict__ s_to,
    const __half* __restrict__ mh, int n_nodes, float* __restrict__ out) {
  const int lane = threadIdx.x & 63;
  const int v = blockIdx.x * 4 + (threadIdx.x >> 6);
  if (v >= n_nodes) return;
  const int start = row_start[v];
  const int end = row_start[v + 1];
  if (start >= end) return;  // degree 0: d_out row already = passthrough
  const float st = s_to[v];

  float wsum = 0.f;
  float ax = 0.f, ay = 0.f;  // lane owns columns 2*lane, 2*lane+1
  for (int cbase = start; cbase < end; cbase += 64) {
    const int cnt = min(64, end - cbase);
    int s = 0;
    float w = 0.f;
    if (lane < cnt) {
      s = srcs[cbase + lane];
      float xx = s_from[s] + st;
      xx = (xx >= 0.f) ? xx : LEAKY * xx;
      w = __expf(xx);  // no max-sub: softmax shift-invariant, e is O(1)
    }
    wsum += w;
#pragma unroll 8
    for (int i = 0; i < cnt; ++i) {   // branch-free body -> loads pipeline
      int si = __shfl(s, i, 64);
      float wi = __shfl(w, i, 64);
      const float2 mf =
          __half22float2(((const __half2*)(mh + (size_t)si * DD))[lane]);
      ax = fmaf(wi, mf.x, ax);
      ay = fmaf(wi, mf.y, ay);
    }
  }
#pragma unroll
  for (int m = 32; m; m >>= 1) wsum += __shfl_xor(wsum, m, 64);
  const float inv = 1.f / wsum;
  ax *= inv; ay *= inv;
  ax = (ax > 0.f) ? ax : 0.f;  // relu(merged)
  ay = (ay > 0.f) ? ay : 0.f;
  float2* orow = (float2*)(out + (size_t)v * DD);
  float2 po = orow[lane];      // passthrough written by k_msg
  orow[lane] = make_float2(po.x + ax, po.y + ay);
}

// ---------- host ----------
extern "C" void kernel_launch(void* const* d_in, const int* in_sizes, int n_in,
                              void* d_out, int out_size, void* d_ws, size_t ws_size,
                              hipStream_t stream) {
  const float* x = (const float*)d_in[0];
  const int* edges = (const int*)d_in[1];
  const float* Wm = (const float*)d_in[2];
  const float* aw = (const float*)d_in[3];
  const float* Wr = (const float*)d_in[4];
  const float* coef = (const float*)d_in[5];
  float* out = (float*)d_out;

  const int N = in_sizes[0] / DD;  // 100000
  const int E = in_sizes[1] / 2;   // 1600000
  const int nb = (N + BSZ - 1) / BSZ;  // 12500 buckets

  // Workspace budget check: never scribble past d_ws.
  const size_t need = ((size_t)N * DD * 2 + 256)       // mh (fp16 messages)
                    + 2 * ((size_t)N * 4 + 256)        // s_from, s_to
                    + 2 * ((size_t)DD * DD * 4 + 256)  // WTm, WTr
                    + 3 * ((size_t)(nb + 1) * 4 + 512) // bcnt, bstart, bcursor
                    + ((size_t)(N + 1) * 4 + 256)      // row_start
                    + 1024                              // flags
                    + 2 * ((size_t)E * 4 + 256);        // packed, srcs
  if (ws_size < need) return;  // refuse to run rather than corrupt memory

  char* w = (char*)d_ws;
  auto alloc = [&](size_t bytes) {
    char* p = w;
    w += (bytes + 255) & ~(size_t)255;
    return p;
  };
  __half* mh     = (__half*)alloc((size_t)N * DD * 2);
  float* s_from  = (float*)alloc((size_t)N * 4);
  float* s_to    = (float*)alloc((size_t)N * 4);
  float* WTm     = (float*)alloc((size_t)DD * DD * 4);
  float* WTr     = (float*)alloc((size_t)DD * DD * 4);
  int*   bcnt    = (int*)alloc((size_t)nb * 4);
  int*   bstart  = (int*)alloc((size_t)(nb + 1) * 4);
  int*   bcursor = (int*)alloc((size_t)nb * 4);
  int*   row_start = (int*)alloc((size_t)(N + 1) * 4);
  int*   flag    = (int*)alloc(256);   // flag[0]=int64 layout, flag[1]=Wr==I
  int*   packed  = (int*)alloc((size_t)E * 4);
  int*   srcs    = (int*)alloc((size_t)E * 4);

  k_detect<<<1, 64, 0, stream>>>(edges, flag);
  k_eye<<<1, 256, 0, stream>>>(Wr, flag + 1);
  k_transpose2<<<(DD * DD + 255) / 256, 256, 0, stream>>>(Wm, Wr, WTm, WTr);
  k_zero<<<(nb + 255) / 256, 256, 0, stream>>>(bcnt, nb);
  k_msg<<<(N + NPB - 1) / NPB, 256, 0, stream>>>(x, WTm, WTr, aw, coef, flag + 1,
                                                 N, mh, s_from, s_to, out);
  k_bcount<<<(E + 255) / 256, 256, 0, stream>>>(edges, E, N, flag, bcnt);
  k_bscan<<<1, 256, 0, stream>>>(bcnt, nb, bstart, bcursor);
  k_bscatter<<<(E + 255) / 256, 256, 0, stream>>>(edges, E, N, flag, bcursor, packed);
  k_bsort<<<(nb + 3) / 4, 256, 0, stream>>>(bstart, packed, nb, N, E,
                                            srcs, row_start);
  k_nagg<<<(N + 3) / 4, 256, 0, stream>>>(row_start, srcs, s_from, s_to,
                                          mh, N, out);
}

// Round 9
// 445.825 us; speedup vs baseline: 3.1559x; 1.0693x over previous
//
#include <hip/hip_runtime.h>
#include <hip/hip_fp16.h>

// GAT layer: messages = X@Wm^T; e = lrelu(sf[src]+st[dst]); softmax over dst;
// merged = segsum(alpha * messages[src]); out = sig(c)*(X@Wr^T) + relu(merged).
//
// R8 post-mortem: k_nagg is down to 114us but total stuck at ~477 — the
// serial chain of sub-cutoff kernels (msg GEMM + count/scan/scatter/sort +
// 10 launch slots) is ~360us. R9: overlap independent stages via grid-
// partitioned fusion (msg ∥ scatter in one launch; transpose ∥ count;
// detect ∥ eye ∥ zero), replace the single-block 13-chunk scan (1 CU,
// ~16 barriers/chunk) with the 3-level 13-block scan. 10 launches -> 8.

#define DD 128
#define NPB 32           // nodes per block in the GEMM kernel
#define LEAKY 0.01f
#define BSH 3            // log2(nodes per bucket)
#define BSZ 8            // nodes per bucket

#define FMA4(A, XS, W)                                        \
  A.x = fmaf((XS), (W).x, A.x); A.y = fmaf((XS), (W).y, A.y); \
  A.z = fmaf((XS), (W).z, A.z); A.w = fmaf((XS), (W).w, A.w)

// ---------- L0: detect ∥ eye ∥ zero(bcnt)  (fused, independent) ----------
__global__ void k_init(const int* __restrict__ e, const float* __restrict__ Wr,
                       int* __restrict__ flag, int* __restrict__ bcnt, int nb) {
  const int b = blockIdx.x;
  if (b == 0) {
    if (threadIdx.x == 0) {
      int all0 = 1;
      for (int i = 0; i < 64; ++i)
        if (e[2 * i + 1] != 0) { all0 = 0; break; }
      flag[0] = all0;  // 1 -> int64 layout
    }
  } else if (b == 1) {
    // exact check: is W_res the identity? (256 threads, ballot-free)
    __shared__ int ok_s;
    if (threadIdx.x == 0) ok_s = 1;
    __syncthreads();
    int ok = 1;
    for (int i = threadIdx.x; i < DD * DD; i += 256) {
      float expect = ((i >> 7) == (i & (DD - 1))) ? 1.f : 0.f;
      if (Wr[i] != expect) ok = 0;
    }
    if (!ok) ok_s = 0;  // benign race: all writers write 0
    __syncthreads();
    if (threadIdx.x == 0) flag[1] = ok_s;
  } else {
    int i = (b - 2) * 256 + threadIdx.x;
    if (i < nb) bcnt[i] = 0;
  }
}

// ---------- L1: transpose ∥ bucket-count  (fused, independent) ----------
__global__ void k_prep(const float* __restrict__ Wm, const float* __restrict__ Wr,
                       float* __restrict__ WTm, float* __restrict__ WTr,
                       const int* __restrict__ edges, int n_edges, int n_nodes,
                       const int* __restrict__ flag, int* __restrict__ bcnt) {
  const int b = blockIdx.x;
  if (b < 64) {
    int idx = b * 256 + threadIdx.x;
    int j = idx >> 7, k = idx & (DD - 1);
    WTm[k * DD + j] = Wm[idx];   // WT[k][j] = W[j][k]
    WTr[k * DD + j] = Wr[idx];
  } else {
    int i = (b - 64) * 256 + threadIdx.x;
    if (i < n_edges) {
      int d = flag[0] ? ((const int2*)edges)[n_edges + i].x : edges[n_edges + i];
      if ((unsigned)d < (unsigned)n_nodes) atomicAdd(&bcnt[d >> BSH], 1);
    }
  }
}

// ---------- 3-level scan over nb buckets (13 blocks, proven R1 shape) ----------
__global__ __launch_bounds__(256) void k_scan_a(const int* __restrict__ cnt, int n,
                                                int* __restrict__ outp,
                                                int* __restrict__ bsum) {
  __shared__ int lds[256];
  const int t = threadIdx.x;
  const int base = blockIdx.x * 1024 + t * 4;
  int v0 = 0, v1 = 0, v2 = 0, v3 = 0;
  if (base + 3 < n) {
    int4 q = *(const int4*)(cnt + base);
    v0 = q.x; v1 = q.y; v2 = q.z; v3 = q.w;
  } else {
    if (base + 0 < n) v0 = cnt[base + 0];
    if (base + 1 < n) v1 = cnt[base + 1];
    if (base + 2 < n) v2 = cnt[base + 2];
    if (base + 3 < n) v3 = cnt[base + 3];
  }
  const int tsum = v0 + v1 + v2 + v3;
  int val = tsum;
  lds[t] = val;
  __syncthreads();
  for (int off = 1; off < 256; off <<= 1) {
    int a = (t >= off) ? lds[t - off] : 0;
    __syncthreads();
    val += a;
    lds[t] = val;
    __syncthreads();
  }
  int o0 = val - tsum;
  int o1 = o0 + v0, o2 = o1 + v1, o3 = o2 + v2;
  if (base + 0 < n) outp[base + 0] = o0;
  if (base + 1 < n) outp[base + 1] = o1;
  if (base + 2 < n) outp[base + 2] = o2;
  if (base + 3 < n) outp[base + 3] = o3;
  if (t == 255) bsum[blockIdx.x] = val;  // block total
}

__global__ void k_scan_b(int* __restrict__ bsum, int nbk,
                         int* __restrict__ bstart, int nb) {
  __shared__ int lds[256];
  const int t = threadIdx.x;
  int v = (t < nbk) ? bsum[t] : 0;
  int val = v;
  lds[t] = val;
  __syncthreads();
  for (int off = 1; off < 256; off <<= 1) {
    int a = (t >= off) ? lds[t - off] : 0;
    __syncthreads();
    val += a;
    lds[t] = val;
    __syncthreads();
  }
  if (t < nbk) bsum[t] = val - v;            // exclusive
  if (t == nbk - 1) bstart[nb] = val;        // grand total (robust)
}

__global__ void k_scan_c(int* __restrict__ bstart, int* __restrict__ bcursor,
                         const int* __restrict__ bsum, int nb) {
  const int off = bsum[blockIdx.x];
  const int base = blockIdx.x * 1024 + threadIdx.x * 4;
#pragma unroll
  for (int c = 0; c < 4; ++c) {
    int idx = base + c;
    if (idx < nb) {
      int r = bstart[idx] + off;
      bstart[idx] = r;
      bcursor[idx] = r;
    }
  }
}

// ---------- L5: msg GEMM ∥ bucket scatter  (fused, independent) ----------
__global__ __launch_bounds__(256) void k_mscat(
    const float* __restrict__ x, const float* __restrict__ WTm,
    const float* __restrict__ WTr, const float* __restrict__ attn_w,
    const float* __restrict__ coef, const int* __restrict__ flag, int n_nodes,
    __half* __restrict__ mh, float* __restrict__ s_from,
    float* __restrict__ s_to, float* __restrict__ out, int msg_blocks,
    const int* __restrict__ edges, int n_edges, int* __restrict__ bcursor,
    int* __restrict__ packed) {
  __shared__ float4 lw4[32 * 32];    // 16 KiB
  __shared__ float4 lx4[NPB * 32];   // 16 KiB
  __shared__ float lds_aw[2 * DD];   // 1 KiB
  const int t = threadIdx.x;

  if ((int)blockIdx.x >= msg_blocks) {
    // ---- scatter part: packed (src<<BSH | dst&7) into bucket regions ----
    // Write frontier = nb lines = 800 KB -> L2-resident.
    int i = (blockIdx.x - msg_blocks) * 256 + t;
    if (i < n_edges) {
      int d, s;
      if (flag[0]) {
        d = ((const int2*)edges)[n_edges + i].x;
        s = ((const int2*)edges)[i].x;
      } else {
        d = edges[n_edges + i];
        s = edges[i];
      }
      if ((unsigned)d < (unsigned)n_nodes) {
        if ((unsigned)s >= (unsigned)n_nodes) s = 0;
        int pos = atomicAdd(&bcursor[d >> BSH], 1);
        packed[pos] = (s << BSH) | (d & (BSZ - 1));
      }
    }
    return;
  }

  // ---- msg part (identical to proven R2-R8 k_msg) ----
  const int base = blockIdx.x * NPB;
  const int nvalid = min(NPB, n_nodes - base);

  const float4* xs = (const float4*)(x + (size_t)base * DD);
  const int nflt4 = nvalid * 32;
  for (int i = t; i < nflt4; i += 256) lx4[i] = xs[i];
  if (t < 2 * DD) lds_aw[t] = attn_w[t];

  const int j4 = t & 31;
  const int g = t >> 5;
  const int r0 = (g * 4 + 0) * 32, r1 = r0 + 32, r2 = r1 + 32, r3 = r2 + 32;

  float4 a0, a1, a2, a3;

  // Named accumulators, bounded unroll -> no spill (R1 lesson).
#define GEMM128(WT)                                                           \
  a0 = a1 = a2 = a3 = make_float4(0.f, 0.f, 0.f, 0.f);                        \
  _Pragma("unroll 1")                                                         \
  for (int chunk = 0; chunk < 4; ++chunk) {                                   \
    __syncthreads();                                                          \
    const float4* wsrc = (const float4*)((WT) + chunk * 32 * DD);             \
    lw4[t] = wsrc[t];                                                         \
    lw4[t + 256] = wsrc[t + 256];                                             \
    lw4[t + 512] = wsrc[t + 512];                                             \
    lw4[t + 768] = wsrc[t + 768];                                             \
    __syncthreads();                                                          \
    const int xb = chunk * 8;                                                 \
    _Pragma("unroll 2")                                                       \
    for (int k = 0; k < 32; k += 4) {                                         \
      float4 w0 = lw4[(k + 0) * 32 + j4];                                     \
      float4 w1 = lw4[(k + 1) * 32 + j4];                                     \
      float4 w2 = lw4[(k + 2) * 32 + j4];                                     \
      float4 w3 = lw4[(k + 3) * 32 + j4];                                     \
      float4 x0 = lx4[r0 + xb + (k >> 2)];                                    \
      float4 x1 = lx4[r1 + xb + (k >> 2)];                                    \
      float4 x2 = lx4[r2 + xb + (k >> 2)];                                    \
      float4 x3 = lx4[r3 + xb + (k >> 2)];                                    \
      FMA4(a0, x0.x, w0); FMA4(a0, x0.y, w1);                                 \
      FMA4(a0, x0.z, w2); FMA4(a0, x0.w, w3);                                 \
      FMA4(a1, x1.x, w0); FMA4(a1, x1.y, w1);                                 \
      FMA4(a1, x1.z, w2); FMA4(a1, x1.w, w3);                                 \
      FMA4(a2, x2.x, w0); FMA4(a2, x2.y, w1);                                 \
      FMA4(a2, x2.z, w2); FMA4(a2, x2.w, w3);                                 \
      FMA4(a3, x3.x, w0); FMA4(a3, x3.y, w1);                                 \
      FMA4(a3, x3.z, w2); FMA4(a3, x3.w, w3);                                 \
    }                                                                         \
  }

  // phase A: messages (fp16 store) + attention scores
  GEMM128(WTm);
  {
    float4 av[4] = {a0, a1, a2, a3};
#pragma unroll
    for (int b = 0; b < 4; ++b) {
      int n = g * 4 + b;
      if (n < nvalid) {
        int gn = base + n;
        float4 v = av[b];
        union { __half2 h2[2]; uint2 u; } pk;
        pk.h2[0] = __floats2half2_rn(v.x, v.y);
        pk.h2[1] = __floats2half2_rn(v.z, v.w);
        ((uint2*)(mh + (size_t)gn * DD))[j4] = pk.u;
        float sf = v.x * lds_aw[4 * j4] + v.y * lds_aw[4 * j4 + 1] +
                   v.z * lds_aw[4 * j4 + 2] + v.w * lds_aw[4 * j4 + 3];
        float stv = v.x * lds_aw[DD + 4 * j4] + v.y * lds_aw[DD + 4 * j4 + 1] +
                    v.z * lds_aw[DD + 4 * j4 + 2] + v.w * lds_aw[DD + 4 * j4 + 3];
#pragma unroll
        for (int m = 16; m; m >>= 1) {
          sf += __shfl_xor(sf, m, 32);
          stv += __shfl_xor(stv, m, 32);
        }
        if (j4 == 0) { s_from[gn] = sf; s_to[gn] = stv; }
      }
    }
  }

  // phase B: passthrough
  const float sig = 1.f / (1.f + __expf(-coef[0]));
  if (flag[1]) {
    // W_res == I: passthrough = sig * x. lds_x intact.
    float4* od = (float4*)(out + (size_t)base * DD);
    for (int i = t; i < nflt4; i += 256) {
      float4 v = lx4[i];
      v.x *= sig; v.y *= sig; v.z *= sig; v.w *= sig;
      od[i] = v;
    }
  } else {
    GEMM128(WTr);
    float4 av[4] = {a0, a1, a2, a3};
#pragma unroll
    for (int b = 0; b < 4; ++b) {
      int n = g * 4 + b;
      if (n < nvalid) {
        int gn = base + n;
        float4 v = av[b];
        v.x *= sig; v.y *= sig; v.z *= sig; v.w *= sig;
        ((float4*)(out + (size_t)gn * DD))[j4] = v;
      }
    }
  }
#undef GEMM128
}

// ---------- within-bucket counting sort -> node-sorted CSR ----------
__global__ __launch_bounds__(256) void k_bsort(
    const int* __restrict__ bstart, const int* __restrict__ packed,
    int nb, int n_nodes, int n_edges_total,
    int* __restrict__ srcs, int* __restrict__ row_start) {
  const int lane = threadIdx.x & 63;
  const int b = blockIdx.x * 4 + (threadIdx.x >> 6);
  if (b >= nb) return;
  const int start = bstart[b], end = bstart[b + 1];
  const int nbase = b << BSH;
  if (b == 0 && lane == 0) row_start[n_nodes] = n_edges_total;

  // pass 1: per-dl counts via ballots (wave-uniform)
  int c0 = 0, c1 = 0, c2 = 0, c3 = 0, c4 = 0, c5 = 0, c6 = 0, c7 = 0;
  for (int cb = start; cb < end; cb += 64) {
    const bool act = (cb + lane) < end;
    const int u = act ? packed[cb + lane] : 0;
    const int dl = u & (BSZ - 1);
    const unsigned long long b0 = __ballot(act && (dl & 1));
    const unsigned long long b1 = __ballot(act && (dl & 2));
    const unsigned long long b2 = __ballot(act && (dl & 4));
    const unsigned long long ba = __ballot(act);
    c0 += __popcll(~b0 & ~b1 & ~b2 & ba);
    c1 += __popcll( b0 & ~b1 & ~b2 & ba);
    c2 += __popcll(~b0 &  b1 & ~b2 & ba);
    c3 += __popcll( b0 &  b1 & ~b2 & ba);
    c4 += __popcll(~b0 & ~b1 &  b2 & ba);
    c5 += __popcll( b0 & ~b1 &  b2 & ba);
    c6 += __popcll(~b0 &  b1 &  b2 & ba);
    c7 += __popcll( b0 &  b1 &  b2 & ba);
  }
  const int o0 = 0, o1 = o0 + c0, o2 = o1 + c1, o3 = o2 + c2, o4 = o3 + c3,
            o5 = o4 + c4, o6 = o5 + c5, o7 = o6 + c6;
  if (lane == 0) {
    if (nbase + 0 < n_nodes) row_start[nbase + 0] = start + o0;
    if (nbase + 1 < n_nodes) row_start[nbase + 1] = start + o1;
    if (nbase + 2 < n_nodes) row_start[nbase + 2] = start + o2;
    if (nbase + 3 < n_nodes) row_start[nbase + 3] = start + o3;
    if (nbase + 4 < n_nodes) row_start[nbase + 4] = start + o4;
    if (nbase + 5 < n_nodes) row_start[nbase + 5] = start + o5;
    if (nbase + 6 < n_nodes) row_start[nbase + 6] = start + o6;
    if (nbase + 7 < n_nodes) row_start[nbase + 7] = start + o7;
  }
  // pass 2: stable scatter within the bucket
  int r0 = o0, r1 = o1, r2 = o2, r3 = o3, r4 = o4, r5 = o5, r6 = o6, r7 = o7;
  for (int cb = start; cb < end; cb += 64) {
    const bool act = (cb + lane) < end;
    const int u = act ? packed[cb + lane] : 0;
    const int dl = u & (BSZ - 1);
    const unsigned long long b0 = __ballot(act && (dl & 1));
    const unsigned long long b1 = __ballot(act && (dl & 2));
    const unsigned long long b2 = __ballot(act && (dl & 4));
    const unsigned long long ba = __ballot(act);
    const unsigned long long m0 = (dl & 1) ? b0 : ~b0;
    const unsigned long long m1 = (dl & 2) ? b1 : ~b1;
    const unsigned long long m2 = (dl & 4) ? b2 : ~b2;
    const unsigned long long mymask = m0 & m1 & m2 & ba;
    const int rank = __popcll(mymask & ((1ull << lane) - 1ull));
    int basep = r0;
    basep = (dl == 1) ? r1 : basep;
    basep = (dl == 2) ? r2 : basep;
    basep = (dl == 3) ? r3 : basep;
    basep = (dl == 4) ? r4 : basep;
    basep = (dl == 5) ? r5 : basep;
    basep = (dl == 6) ? r6 : basep;
    basep = (dl == 7) ? r7 : basep;
    if (act) srcs[start + basep + rank] = u >> BSH;
    r0 += __popcll(~b0 & ~b1 & ~b2 & ba);
    r1 += __popcll( b0 & ~b1 & ~b2 & ba);
    r2 += __popcll(~b0 &  b1 & ~b2 & ba);
    r3 += __popcll( b0 &  b1 & ~b2 & ba);
    r4 += __popcll(~b0 & ~b1 &  b2 & ba);
    r5 += __popcll( b0 & ~b1 &  b2 & ba);
    r6 += __popcll(~b0 &  b1 &  b2 & ba);
    r7 += __popcll( b0 &  b1 &  b2 & ba);
  }
}

// ---------- aggregation: one wave per node, branch-free, fp16 gather ----------
__global__ __launch_bounds__(256) void k_nagg(
    const int* __restrict__ row_start, const int* __restrict__ srcs,
    const float* __restrict__ s_from, const float* __restrict__ s_to,
    const __half* __restrict__ mh, int n_nodes, float* __restrict__ out) {
  const int lane = threadIdx.x & 63;
  const int v = blockIdx.x * 4 + (threadIdx.x >> 6);
  if (v >= n_nodes) return;
  const int start = row_start[v];
  const int end = row_start[v + 1];
  if (start >= end) return;  // degree 0: d_out row already = passthrough
  const float st = s_to[v];

  float wsum = 0.f;
  float ax = 0.f, ay = 0.f;  // lane owns columns 2*lane, 2*lane+1
  for (int cbase = start; cbase < end; cbase += 64) {
    const int cnt = min(64, end - cbase);
    int s = 0;
    float w = 0.f;
    if (lane < cnt) {
      s = srcs[cbase + lane];
      float xx = s_from[s] + st;
      xx = (xx >= 0.f) ? xx : LEAKY * xx;
      w = __expf(xx);  // no max-sub: softmax shift-invariant, e is O(1)
    }
    wsum += w;
#pragma unroll 8
    for (int i = 0; i < cnt; ++i) {   // branch-free body -> loads pipeline
      int si = __shfl(s, i, 64);
      float wi = __shfl(w, i, 64);
      const float2 mf =
          __half22float2(((const __half2*)(mh + (size_t)si * DD))[lane]);
      ax = fmaf(wi, mf.x, ax);
      ay = fmaf(wi, mf.y, ay);
    }
  }
#pragma unroll
  for (int m = 32; m; m >>= 1) wsum += __shfl_xor(wsum, m, 64);
  const float inv = 1.f / wsum;
  ax *= inv; ay *= inv;
  ax = (ax > 0.f) ? ax : 0.f;  // relu(merged)
  ay = (ay > 0.f) ? ay : 0.f;
  float2* orow = (float2*)(out + (size_t)v * DD);
  float2 po = orow[lane];      // passthrough written by msg phase
  orow[lane] = make_float2(po.x + ax, po.y + ay);
}

// ---------- host ----------
extern "C" void kernel_launch(void* const* d_in, const int* in_sizes, int n_in,
                              void* d_out, int out_size, void* d_ws, size_t ws_size,
                              hipStream_t stream) {
  const float* x = (const float*)d_in[0];
  const int* edges = (const int*)d_in[1];
  const float* Wm = (const float*)d_in[2];
  const float* aw = (const float*)d_in[3];
  const float* Wr = (const float*)d_in[4];
  const float* coef = (const float*)d_in[5];
  float* out = (float*)d_out;

  const int N = in_sizes[0] / DD;  // 100000
  const int E = in_sizes[1] / 2;   // 1600000
  const int nb = (N + BSZ - 1) / BSZ;  // 12500 buckets

  // Workspace budget check: never scribble past d_ws.
  const size_t need = ((size_t)N * DD * 2 + 256)       // mh (fp16 messages)
                    + 2 * ((size_t)N * 4 + 256)        // s_from, s_to
                    + 2 * ((size_t)DD * DD * 4 + 256)  // WTm, WTr
                    + 3 * ((size_t)(nb + 1) * 4 + 512) // bcnt, bstart, bcursor
                    + ((size_t)(N + 1) * 4 + 256)      // row_start
                    + 2048                              // flags + bsum
                    + 2 * ((size_t)E * 4 + 256);        // packed, srcs
  if (ws_size < need) return;  // refuse to run rather than corrupt memory

  char* w = (char*)d_ws;
  auto alloc = [&](size_t bytes) {
    char* p = w;
    w += (bytes + 255) & ~(size_t)255;
    return p;
  };
  __half* mh     = (__half*)alloc((size_t)N * DD * 2);
  float* s_from  = (float*)alloc((size_t)N * 4);
  float* s_to    = (float*)alloc((size_t)N * 4);
  float* WTm     = (float*)alloc((size_t)DD * DD * 4);
  float* WTr     = (float*)alloc((size_t)DD * DD * 4);
  int*   bcnt    = (int*)alloc((size_t)nb * 4);
  int*   bstart  = (int*)alloc((size_t)(nb + 1) * 4);
  int*   bcursor = (int*)alloc((size_t)nb * 4);
  int*   row_start = (int*)alloc((size_t)(N + 1) * 4);
  int*   flag    = (int*)alloc(256);   // flag[0]=int64 layout, flag[1]=Wr==I
  int*   bsum    = (int*)alloc(256 * 4);
  int*   packed  = (int*)alloc((size_t)E * 4);
  int*   srcs    = (int*)alloc((size_t)E * 4);

  const int MB = (N + NPB - 1) / NPB;      // 3125 msg blocks
  const int EB = (E + 255) / 256;          // 6250 edge blocks
  const int ZB = (nb + 255) / 256;         // 49 zero blocks
  const int SB = (nb + 1023) / 1024;       // 13 scan blocks

  // L0: detect ∥ eye ∥ zero(bcnt)
  k_init<<<2 + ZB, 256, 0, stream>>>(edges, Wr, flag, bcnt, nb);
  // L1: transpose ∥ bucket-count
  k_prep<<<64 + EB, 256, 0, stream>>>(Wm, Wr, WTm, WTr, edges, E, N, flag, bcnt);
  // L2-L4: 3-level scan (13 blocks wide, not single-block)
  k_scan_a<<<SB, 256, 0, stream>>>(bcnt, nb, bstart, bsum);
  k_scan_b<<<1, 256, 0, stream>>>(bsum, SB, bstart, nb);
  k_scan_c<<<SB, 256, 0, stream>>>(bstart, bcursor, bsum, nb);
  // L5: msg GEMM ∥ scatter (scatter hides under the GEMM)
  k_mscat<<<MB + EB, 256, 0, stream>>>(x, WTm, WTr, aw, coef, flag, N,
                                       mh, s_from, s_to, out, MB,
                                       edges, E, bcursor, packed);
  // L6: within-bucket sort -> node CSR
  k_bsort<<<(nb + 3) / 4, 256, 0, stream>>>(bstart, packed, nb, N, E,
                                            srcs, row_start);
  // L7: aggregation
  k_nagg<<<(N + 3) / 4, 256, 0, stream>>>(row_start, srcs, s_from, s_to,
                                          mh, N, out);
}